// Round 2
// baseline (1583.954 us; speedup 1.0000x reference)
//
#include <hip/hip_runtime.h>
#include <hip/hip_bf16.h>

#define BB 4
#define TT 4096
#define CC 1024
#define HH 64

// ---------------------------------------------------------------------------
// Kernel 1: qkv projection.  grid = (B*T)/16 blocks x 256 threads.
// Each block: 16 rows of x staged to LDS (f32, 64KB). Wave w computes rows
// w*4..w*4+3, lane = output feature index h (64 lanes = 64 outputs, W loads
// coalesced). Outputs: q,v row-major fp32; k stored transposed [b][d][t].
// ---------------------------------------------------------------------------
__global__ __launch_bounds__(256)
void qkv_proj_kernel(const float* __restrict__ x,
                     const float* __restrict__ Wq, const float* __restrict__ bq,
                     const float* __restrict__ Wk, const float* __restrict__ bk,
                     const float* __restrict__ Wv, const float* __restrict__ bv,
                     float* __restrict__ qo, float* __restrict__ kTo,
                     float* __restrict__ vo)
{
    __shared__ float xs[16*CC];           // 64 KB
    const int tid = threadIdx.x;
    const int r0  = blockIdx.x * 16;

    // stage 16 rows (16*1024 f32 = 4096 uint4 chunks), coalesced
    const uint4* xsrc = (const uint4*)(x + (size_t)r0 * CC);
    uint4* xdst = (uint4*)xs;
    #pragma unroll
    for (int k2 = 0; k2 < 16; ++k2)
        xdst[k2*256 + tid] = xsrc[k2*256 + tid];
    __syncthreads();

    const int w = tid >> 6, lane = tid & 63;
    float aq[4], ak[4], av[4];
    const float bqf = bq[lane];
    const float bkf = bk[lane];
    const float bvf = bv[lane];
    #pragma unroll
    for (int j = 0; j < 4; ++j) { aq[j]=bqf; ak[j]=bkf; av[j]=bvf; }

    const float* xw = xs + (w*4)*CC;
    #pragma unroll 2
    for (int c = 0; c < CC; ++c) {
        const float wq = Wq[c*HH + lane];
        const float wk = Wk[c*HH + lane];
        const float wv = Wv[c*HH + lane];
        #pragma unroll
        for (int j = 0; j < 4; ++j) {
            const float xv = xw[j*CC + c];
            aq[j] = fmaf(xv, wq, aq[j]);
            ak[j] = fmaf(xv, wk, ak[j]);
            av[j] = fmaf(xv, wv, av[j]);
        }
    }

    #pragma unroll
    for (int j = 0; j < 4; ++j) {
        const int row = r0 + w*4 + j;
        const int b = row >> 12, t = row & (TT-1);
        qo[(size_t)row*HH + lane] = aq[j];
        vo[(size_t)row*HH + lane] = av[j];
        kTo[((size_t)b*HH + lane)*TT + t] = ak[j];
    }
}

// ---------------------------------------------------------------------------
// Kernel 2: causal flash attention, online softmax.
// grid = (B*T)/32 blocks x 256 threads (4 waves). Block handles 32 q-rows
// (8 rows/wave). Per 64-wide s-chunk: stage ks[d][s], vs[s][d] in LDS.
// Phase1 lane=s (scores), softmax via wave shfl reductions, phase2 lane=d
// (PV accumulate, p broadcast via shfl).
// ---------------------------------------------------------------------------
__global__ __launch_bounds__(256)
void attn_kernel(const float* __restrict__ q, const float* __restrict__ kT,
                 const float* __restrict__ v, float* __restrict__ out)
{
    __shared__ float qs[32*HH];   // 8 KB
    __shared__ float ks[64*64];   // 16 KB  ks[d][s]
    __shared__ float vs[64*64];   // 16 KB  vs[s][d]

    const int tid = threadIdx.x, w = tid >> 6, lane = tid & 63;
    const int row0 = blockIdx.x * 32;            // blocks never straddle batch
    const int b  = row0 >> 12;
    const int i0 = row0 & (TT-1);

    // stage q tile (2048 floats)
    const float* qg = q + (size_t)row0*HH;
    #pragma unroll
    for (int k2 = 0; k2 < 8; ++k2)
        qs[k2*256 + tid] = qg[k2*256 + tid];

    const float* ktb = kT + (size_t)b*HH*TT;
    const float* vb  = v  + (size_t)b*TT*HH;

    float o[8], m[8], l[8];
    #pragma unroll
    for (int j = 0; j < 8; ++j) { o[j]=0.f; m[j]=-1e30f; l[j]=0.f; }

    const int nch = ((i0 + 31) >> 6) + 1;
    for (int ch = 0; ch < nch; ++ch) {
        const int s0 = ch << 6;
        __syncthreads();   // protect prior reads (and q staging on ch==0)
        #pragma unroll
        for (int k2 = 0; k2 < 16; ++k2) {
            const int f = k2*256 + tid;
            ks[f] = ktb[(size_t)(f >> 6)*TT + s0 + (f & 63)];
            vs[f] = vb[(size_t)s0*HH + f];
        }
        __syncthreads();

        // phase 1: scores, lane = s
        float sc[8];
        #pragma unroll
        for (int j = 0; j < 8; ++j) sc[j] = 0.f;
        const float* qsw = qs + (w*8)*HH;
        for (int d = 0; d < 64; ++d) {
            const float kd = ks[d*64 + lane];
            #pragma unroll
            for (int j = 0; j < 8; ++j)
                sc[j] = fmaf(qsw[j*HH + d], kd, sc[j]);
        }

        // online softmax per row
        #pragma unroll
        for (int j = 0; j < 8; ++j) {
            const int i = i0 + w*8 + j;
            float s_ = sc[j] * 0.125f;               // 1/sqrt(64)
            if (s0 + lane > i) s_ = -1e30f;          // causal mask
            float cm = s_;
            #pragma unroll
            for (int off = 32; off; off >>= 1) cm = fmaxf(cm, __shfl_xor(cm, off));
            const float mn = fmaxf(m[j], cm);
            const float alpha = __expf(m[j] - mn);
            const float p = __expf(s_ - mn);
            float cs = p;
            #pragma unroll
            for (int off = 32; off; off >>= 1) cs += __shfl_xor(cs, off);
            l[j] = l[j]*alpha + cs;
            o[j] *= alpha;
            m[j] = mn;
            sc[j] = p;
        }

        // phase 2: PV, lane = d
        for (int s = 0; s < 64; ++s) {
            const float vv = vs[s*64 + lane];
            #pragma unroll
            for (int j = 0; j < 8; ++j)
                o[j] = fmaf(__shfl(sc[j], s), vv, o[j]);
        }
    }

    #pragma unroll
    for (int j = 0; j < 8; ++j) {
        const int row = row0 + w*8 + j;
        out[(size_t)row*HH + lane] = o[j] / l[j];
    }
}

extern "C" void kernel_launch(void* const* d_in, const int* in_sizes, int n_in,
                              void* d_out, int out_size, void* d_ws, size_t ws_size,
                              hipStream_t stream) {
    (void)in_sizes; (void)n_in; (void)out_size; (void)ws_size;
    const float* x  = (const float*)d_in[0];
    // d_in[1] = causal mask, structural -> unused
    const float* Wq = (const float*)d_in[2];
    const float* bq = (const float*)d_in[3];
    const float* Wk = (const float*)d_in[4];
    const float* bk = (const float*)d_in[5];
    const float* Wv = (const float*)d_in[6];
    const float* bv = (const float*)d_in[7];
    float* out = (float*)d_out;

    float* qf  = (float*)d_ws;                        // 4 MB
    float* kTf = qf  + (size_t)BB*TT*HH;              // 4 MB
    float* vf  = kTf + (size_t)BB*TT*HH;              // 4 MB

    qkv_proj_kernel<<<(BB*TT)/16, 256, 0, stream>>>(x, Wq, bq, Wk, bk, Wv, bv,
                                                    qf, kTf, vf);
    attn_kernel<<<(BB*TT)/32, 256, 0, stream>>>(qf, kTf, vf, out);
}

// Round 3
// 330.709 us; speedup vs baseline: 4.7896x; 4.7896x over previous
//
#include <hip/hip_runtime.h>
#include <hip/hip_bf16.h>

#define BB 4
#define TT 4096
#define CC 1024
#define HH 64

typedef __attribute__((ext_vector_type(8))) short short8;   // 8 x bf16 (4 VGPRs)
typedef __attribute__((ext_vector_type(4))) float floatx4;  // MFMA C/D

__device__ __forceinline__ ushort f2bf(float f) {
    union { float f; unsigned u; } a; a.f = f;
    const unsigned u = a.u;
    return (ushort)((u + 0x7fffu + ((u >> 16) & 1u)) >> 16);   // RNE
}

// ---------------------------------------------------------------------------
// Kernel A: W [1024 x 64] f32  ->  wT [3][64][1024] bf16 (transposed)
// ---------------------------------------------------------------------------
__global__ __launch_bounds__(256)
void wtrans_kernel(const float* __restrict__ Wq, const float* __restrict__ Wk,
                   const float* __restrict__ Wv, ushort* __restrict__ wT)
{
    const int mat = blockIdx.x >> 6;          // 0..2
    const int n   = blockIdx.x & 63;
    const float* W = (mat == 0) ? Wq : (mat == 1) ? Wk : Wv;
    ushort* dst = wT + ((size_t)mat * 64 + n) * 1024;
    for (int i = threadIdx.x; i < 1024; i += 256)
        dst[i] = f2bf(W[(size_t)i * 64 + n]);
}

// ---------------------------------------------------------------------------
// Kernel B: qkv projection via MFMA.  grid = 16384/64 = 256 blocks x 256 thr.
// Block: 64-row M-tile; wave w -> rows w*16..+15; 12 n-tiles (q,k,v x 4).
// Outputs: q,k row-major bf16 [16384][64]; v transposed vT[b][64][4096] bf16.
// LDS rows padded to 72 bf16 (144B): b128 frag reads land 2-way max.
// ---------------------------------------------------------------------------
__global__ __launch_bounds__(256)
void qkv_mfma_kernel(const float* __restrict__ x, const ushort* __restrict__ wT,
                     const float* __restrict__ bq, const float* __restrict__ bk,
                     const float* __restrict__ bv,
                     ushort* __restrict__ q, ushort* __restrict__ k,
                     ushort* __restrict__ vT)
{
    __shared__ ushort xs [64 * 72];
    __shared__ ushort wqs[64 * 72];
    __shared__ ushort wks[64 * 72];
    __shared__ ushort wvs[64 * 72];

    const int tid = threadIdx.x, w = tid >> 6, lane = tid & 63;
    const int m = lane & 15, quad = lane >> 4;
    const int row0 = blockIdx.x * 64;

    floatx4 acc[12];
    #pragma unroll
    for (int i = 0; i < 12; ++i) acc[i] = (floatx4){0.f, 0.f, 0.f, 0.f};

    for (int kc = 0; kc < 16; ++kc) {
        const int k0 = kc * 64;
        __syncthreads();
        // stage x chunk (64 rows x 64 k), f32 -> bf16
        #pragma unroll
        for (int it = 0; it < 4; ++it) {
            const int t2 = it * 256 + tid;
            const int r = t2 >> 4, seg = t2 & 15;
            const float4 xv = *(const float4*)(x + (size_t)(row0 + r) * CC + k0 + seg * 4);
            ushort4 p; p.x = f2bf(xv.x); p.y = f2bf(xv.y); p.z = f2bf(xv.z); p.w = f2bf(xv.w);
            *(ushort4*)(xs + r * 72 + seg * 4) = p;
        }
        // stage 3 W chunks (bf16 straight copy)
        #pragma unroll
        for (int it = 0; it < 2; ++it) {
            const int t2 = it * 256 + tid;
            const int r = t2 >> 3, seg = t2 & 7;
            *(uint4*)(wqs + r * 72 + seg * 8) = *(const uint4*)(wT + ((size_t)0 * 64 + r) * 1024 + k0 + seg * 8);
            *(uint4*)(wks + r * 72 + seg * 8) = *(const uint4*)(wT + ((size_t)1 * 64 + r) * 1024 + k0 + seg * 8);
            *(uint4*)(wvs + r * 72 + seg * 8) = *(const uint4*)(wT + ((size_t)2 * 64 + r) * 1024 + k0 + seg * 8);
        }
        __syncthreads();

        #pragma unroll
        for (int ks_ = 0; ks_ < 2; ++ks_) {
            const short8 a = *(const short8*)(xs + (w * 16 + m) * 72 + ks_ * 32 + quad * 8);
            #pragma unroll
            for (int nt = 0; nt < 4; ++nt) {
                const short8 b0 = *(const short8*)(wqs + (nt * 16 + m) * 72 + ks_ * 32 + quad * 8);
                acc[nt]     = __builtin_amdgcn_mfma_f32_16x16x32_bf16(a, b0, acc[nt],     0, 0, 0);
                const short8 b1 = *(const short8*)(wks + (nt * 16 + m) * 72 + ks_ * 32 + quad * 8);
                acc[4 + nt] = __builtin_amdgcn_mfma_f32_16x16x32_bf16(a, b1, acc[4 + nt], 0, 0, 0);
                const short8 b2 = *(const short8*)(wvs + (nt * 16 + m) * 72 + ks_ * 32 + quad * 8);
                acc[8 + nt] = __builtin_amdgcn_mfma_f32_16x16x32_bf16(a, b2, acc[8 + nt], 0, 0, 0);
            }
        }
    }

    // epilogue: bias + store.  C-layout: col = nt*16 + m, row = quad*4 + reg.
    const int gr0 = row0 + w * 16 + quad * 4;
    const int b = gr0 >> 12, t0 = gr0 & (TT - 1);
    #pragma unroll
    for (int nt = 0; nt < 4; ++nt) {
        const int col = nt * 16 + m;
        const float bqv = bq[col], bkv = bk[col], bvv = bv[col];
        #pragma unroll
        for (int r = 0; r < 4; ++r) {
            q[(size_t)(gr0 + r) * HH + col] = f2bf(acc[nt][r] + bqv);
            k[(size_t)(gr0 + r) * HH + col] = f2bf(acc[4 + nt][r] + bkv);
        }
        ushort4 pv;
        pv.x = f2bf(acc[8 + nt][0] + bvv); pv.y = f2bf(acc[8 + nt][1] + bvv);
        pv.z = f2bf(acc[8 + nt][2] + bvv); pv.w = f2bf(acc[8 + nt][3] + bvv);
        *(ushort4*)(vT + ((size_t)b * HH + col) * TT + t0) = pv;
    }
}

// ---------------------------------------------------------------------------
// Kernel C: causal flash attention via MFMA.  grid = 4*64 = 256 blocks.
// Block: 64-row q-tile, wave w -> 16 rows.  s-chunks of 64.
// QK^T: A=q rows, B=k rows (both natural layout).  P round-trips LDS
// (C-layout -> A-layout).  PV: B-frags from vT rows (contiguous s).
// ---------------------------------------------------------------------------
__global__ __launch_bounds__(256)
void attn_mfma_kernel(const ushort* __restrict__ q, const ushort* __restrict__ k,
                      const ushort* __restrict__ vT, float* __restrict__ out)
{
    __shared__ ushort qs[64 * 72];
    __shared__ ushort ks[64 * 72];
    __shared__ ushort vs[64 * 72];        // [d][s] (from vT)
    __shared__ ushort ps[4][16 * 72];     // wave-private P

    const int tid = threadIdx.x, w = tid >> 6, lane = tid & 63;
    const int m = lane & 15, quad = lane >> 4;
    const int b = blockIdx.x >> 6;
    const int tile = blockIdx.x & 63;
    const int i0 = tile * 64;

    // stage q tile
    const size_t qbase = ((size_t)b * TT + i0) * HH;
    #pragma unroll
    for (int it = 0; it < 2; ++it) {
        const int t2 = it * 256 + tid;
        const int r = t2 >> 3, seg = t2 & 7;
        *(uint4*)(qs + r * 72 + seg * 8) = *(const uint4*)(q + qbase + (size_t)r * HH + seg * 8);
    }
    __syncthreads();

    // loop-invariant Q a-frags
    const short8 aq0 = *(const short8*)(qs + (w * 16 + m) * 72 + quad * 8);
    const short8 aq1 = *(const short8*)(qs + (w * 16 + m) * 72 + 32 + quad * 8);

    float mrow[4], lrow[4];
    floatx4 oacc[4];
    #pragma unroll
    for (int r = 0; r < 4; ++r) { mrow[r] = -1e30f; lrow[r] = 0.f; }
    #pragma unroll
    for (int nt = 0; nt < 4; ++nt) oacc[nt] = (floatx4){0.f, 0.f, 0.f, 0.f};

    const int iq0 = i0 + w * 16;
    const int nch = tile + 1;
    for (int ch = 0; ch < nch; ++ch) {
        const int s0 = ch * 64;
        __syncthreads();
        const size_t kb = ((size_t)b * TT + s0) * HH;
        #pragma unroll
        for (int it = 0; it < 2; ++it) {
            const int t2 = it * 256 + tid;
            const int r = t2 >> 3, seg = t2 & 7;
            *(uint4*)(ks + r * 72 + seg * 8) = *(const uint4*)(k + kb + (size_t)r * HH + seg * 8);
            *(uint4*)(vs + r * 72 + seg * 8) = *(const uint4*)(vT + ((size_t)b * HH + r) * TT + s0 + seg * 8);
        }
        __syncthreads();

        // scores: 4 n-tiles x 2 k-steps
        floatx4 sc[4];
        #pragma unroll
        for (int nt = 0; nt < 4; ++nt) {
            const short8 b0 = *(const short8*)(ks + (nt * 16 + m) * 72 + quad * 8);
            const short8 b1 = *(const short8*)(ks + (nt * 16 + m) * 72 + 32 + quad * 8);
            floatx4 s_ = (floatx4){0.f, 0.f, 0.f, 0.f};
            s_ = __builtin_amdgcn_mfma_f32_16x16x32_bf16(aq0, b0, s_, 0, 0, 0);
            s_ = __builtin_amdgcn_mfma_f32_16x16x32_bf16(aq1, b1, s_, 0, 0, 0);
            sc[nt] = s_;
        }

        // online softmax (C-layout: col = nt*16+m, row = quad*4+r)
        #pragma unroll
        for (int r = 0; r < 4; ++r) {
            const int irow = iq0 + quad * 4 + r;
            float v0 = sc[0][r] * 0.125f, v1 = sc[1][r] * 0.125f;
            float v2 = sc[2][r] * 0.125f, v3 = sc[3][r] * 0.125f;
            if (s0      + m > irow) v0 = -1e30f;
            if (s0 + 16 + m > irow) v1 = -1e30f;
            if (s0 + 32 + m > irow) v2 = -1e30f;
            if (s0 + 48 + m > irow) v3 = -1e30f;
            float mx = fmaxf(fmaxf(v0, v1), fmaxf(v2, v3));
            mx = fmaxf(mx, __shfl_xor(mx, 1));
            mx = fmaxf(mx, __shfl_xor(mx, 2));
            mx = fmaxf(mx, __shfl_xor(mx, 4));
            mx = fmaxf(mx, __shfl_xor(mx, 8));
            const float mn = fmaxf(mrow[r], mx);
            const float alpha = __expf(mrow[r] - mn);
            mrow[r] = mn;
            v0 = __expf(v0 - mn); v1 = __expf(v1 - mn);
            v2 = __expf(v2 - mn); v3 = __expf(v3 - mn);
            float rs = v0 + v1 + v2 + v3;
            rs += __shfl_xor(rs, 1); rs += __shfl_xor(rs, 2);
            rs += __shfl_xor(rs, 4); rs += __shfl_xor(rs, 8);
            lrow[r] = lrow[r] * alpha + rs;
            oacc[0][r] *= alpha; oacc[1][r] *= alpha;
            oacc[2][r] *= alpha; oacc[3][r] *= alpha;
            ushort* pr = ps[w] + (quad * 4 + r) * 72;
            pr[m]      = f2bf(v0);
            pr[16 + m] = f2bf(v1);
            pr[32 + m] = f2bf(v2);
            pr[48 + m] = f2bf(v3);
        }

        // PV: A = P (LDS round-trip), B = vT rows
        #pragma unroll
        for (int ks_ = 0; ks_ < 2; ++ks_) {
            const short8 ap = *(const short8*)(ps[w] + m * 72 + ks_ * 32 + quad * 8);
            #pragma unroll
            for (int nt = 0; nt < 4; ++nt) {
                const short8 bv_ = *(const short8*)(vs + (nt * 16 + m) * 72 + ks_ * 32 + quad * 8);
                oacc[nt] = __builtin_amdgcn_mfma_f32_16x16x32_bf16(ap, bv_, oacc[nt], 0, 0, 0);
            }
        }
    }

    // epilogue
    const size_t obase = ((size_t)b * TT + i0 + w * 16) * HH;
    #pragma unroll
    for (int r = 0; r < 4; ++r) {
        const float inv = 1.0f / lrow[r];
        const int row = quad * 4 + r;
        #pragma unroll
        for (int nt = 0; nt < 4; ++nt)
            out[obase + (size_t)row * HH + nt * 16 + m] = oacc[nt][r] * inv;
    }
}

extern "C" void kernel_launch(void* const* d_in, const int* in_sizes, int n_in,
                              void* d_out, int out_size, void* d_ws, size_t ws_size,
                              hipStream_t stream) {
    (void)in_sizes; (void)n_in; (void)out_size; (void)ws_size;
    const float* x  = (const float*)d_in[0];
    // d_in[1] = causal mask, structural -> unused
    const float* Wq = (const float*)d_in[2];
    const float* bq = (const float*)d_in[3];
    const float* Wk = (const float*)d_in[4];
    const float* bk = (const float*)d_in[5];
    const float* Wv = (const float*)d_in[6];
    const float* bv = (const float*)d_in[7];
    float* out = (float*)d_out;

    ushort* wT  = (ushort*)d_ws;                          // 384 KB
    ushort* qb  = (ushort*)((char*)d_ws + (1 << 19));     // 2 MB
    ushort* kb  = qb + (size_t)BB * TT * HH;              // 2 MB
    ushort* vTb = kb + (size_t)BB * TT * HH;              // 2 MB

    wtrans_kernel  <<<192, 256, 0, stream>>>(Wq, Wk, Wv, wT);
    qkv_mfma_kernel<<<(BB * TT) / 64, 256, 0, stream>>>(x, wT, bq, bk, bv, qb, kb, vTb);
    attn_mfma_kernel<<<BB * 64, 256, 0, stream>>>(qb, kb, vTb, out);
}

// Round 4
// 225.723 us; speedup vs baseline: 7.0172x; 1.4651x over previous
//
#include <hip/hip_runtime.h>
#include <hip/hip_bf16.h>

#define BB 4
#define TT 4096
#define CC 1024
#define HH 64

typedef __attribute__((ext_vector_type(8))) short short8;   // 8 x bf16 (4 VGPRs)
typedef __attribute__((ext_vector_type(4))) float floatx4;  // MFMA C/D

__device__ __forceinline__ ushort f2bf(float f) {
    union { float f; unsigned u; } a; a.f = f;
    const unsigned u = a.u;
    return (ushort)((u + 0x7fffu + ((u >> 16) & 1u)) >> 16);   // RNE
}
__device__ __forceinline__ float bf2f(ushort h) {
    union { unsigned u; float f; } a; a.u = ((unsigned)h) << 16; return a.f;
}

// ---------------------------------------------------------------------------
// Kernel A: W [1024 x 64] f32  ->  wT [3*64][1024] bf16 (transposed, unified)
// ---------------------------------------------------------------------------
__global__ __launch_bounds__(256)
void wtrans_kernel(const float* __restrict__ Wq, const float* __restrict__ Wk,
                   const float* __restrict__ Wv, ushort* __restrict__ wT)
{
    const int mat = blockIdx.x >> 6;          // 0..2
    const int n   = blockIdx.x & 63;
    const float* W = (mat == 0) ? Wq : (mat == 1) ? Wk : Wv;
    ushort* dst = wT + ((size_t)mat * 64 + n) * 1024;
    for (int i = threadIdx.x; i < 1024; i += 256)
        dst[i] = f2bf(W[(size_t)i * 64 + n]);
}

// ---------------------------------------------------------------------------
// Kernel B: qkv projection via MFMA.  grid = 16384/32 = 512 blocks x 512 thr.
// Block: 32-row M-tile, 8 waves. Wave w: m-tile = w>>2 (2 of 16 rows),
// n-quarter = w&3 (48 of 192 unified cols: 0-63 q, 64-127 k, 128-191 v).
// Outputs: q,k row-major bf16; v transposed vT[b][64][4096] bf16.
// LDS rows padded to 72 bf16 -> b128 frag reads 2-way max (free).
// ---------------------------------------------------------------------------
__global__ __launch_bounds__(512)
void qkv_mfma_kernel(const float* __restrict__ x, const ushort* __restrict__ wT,
                     const float* __restrict__ bq, const float* __restrict__ bk,
                     const float* __restrict__ bv,
                     ushort* __restrict__ q, ushort* __restrict__ k,
                     ushort* __restrict__ vT)
{
    __shared__ ushort xs [32 * 72];    // 4.6 KB
    __shared__ ushort ws_[192 * 72];   // 27.6 KB

    const int tid = threadIdx.x, w = tid >> 6, lane = tid & 63;
    const int m = lane & 15, quad = lane >> 4;
    const int mt = w >> 2, nq = w & 3;
    const int row0 = blockIdx.x * 32;

    floatx4 acc[3];
    #pragma unroll
    for (int i = 0; i < 3; ++i) acc[i] = (floatx4){0.f, 0.f, 0.f, 0.f};

    for (int kc = 0; kc < 16; ++kc) {
        const int k0 = kc * 64;
        __syncthreads();
        {   // stage x chunk (32 rows x 64 k) f32 -> bf16 : one float4/thread
            const int r = tid >> 4, seg = tid & 15;
            const float4 xv = *(const float4*)(x + (size_t)(row0 + r) * CC + k0 + seg * 4);
            ushort4 p; p.x = f2bf(xv.x); p.y = f2bf(xv.y); p.z = f2bf(xv.z); p.w = f2bf(xv.w);
            *(ushort4*)(xs + r * 72 + seg * 4) = p;
        }
        // stage W chunk (192 rows x 64 k) : 3 uint4/thread
        #pragma unroll
        for (int it = 0; it < 3; ++it) {
            const int t2 = it * 512 + tid;
            const int r = t2 >> 3, seg = t2 & 7;
            *(uint4*)(ws_ + r * 72 + seg * 8) = *(const uint4*)(wT + (size_t)r * 1024 + k0 + seg * 8);
        }
        __syncthreads();

        #pragma unroll
        for (int ks_ = 0; ks_ < 2; ++ks_) {
            const short8 a = *(const short8*)(xs + (mt * 16 + m) * 72 + ks_ * 32 + quad * 8);
            #pragma unroll
            for (int nt = 0; nt < 3; ++nt) {
                const short8 b_ = *(const short8*)(ws_ + (nq * 48 + nt * 16 + m) * 72 + ks_ * 32 + quad * 8);
                acc[nt] = __builtin_amdgcn_mfma_f32_16x16x32_bf16(a, b_, acc[nt], 0, 0, 0);
            }
        }
    }

    // epilogue: bias + store.  C-layout: col = nq*48+nt*16+m, row = quad*4+r.
    const int gr0 = row0 + mt * 16 + quad * 4;
    const int b = gr0 >> 12, t0 = gr0 & (TT - 1);
    #pragma unroll
    for (int nt = 0; nt < 3; ++nt) {
        const int gcol = nq * 48 + nt * 16 + m;     // 0..191, matrix uniform per nt
        const int mat = gcol >> 6, c = gcol & 63;
        const float bias = (mat == 0) ? bq[c] : (mat == 1) ? bk[c] : bv[c];
        if (mat == 0) {
            #pragma unroll
            for (int r = 0; r < 4; ++r)
                q[(size_t)(gr0 + r) * HH + c] = f2bf(acc[nt][r] + bias);
        } else if (mat == 1) {
            #pragma unroll
            for (int r = 0; r < 4; ++r)
                k[(size_t)(gr0 + r) * HH + c] = f2bf(acc[nt][r] + bias);
        } else {
            ushort4 pv;
            pv.x = f2bf(acc[nt][0] + bias); pv.y = f2bf(acc[nt][1] + bias);
            pv.z = f2bf(acc[nt][2] + bias); pv.w = f2bf(acc[nt][3] + bias);
            *(ushort4*)(vT + ((size_t)b * HH + c) * TT + t0) = pv;
        }
    }
}

// ---------------------------------------------------------------------------
// Kernel C: causal flash attention, 4-way split-s.  grid = 4*64*4 = 1024.
// pid = blockIdx.x; job = pid>>2 (b*64+tile); split = pid&3.
// Block: 64-row q-tile, 4 waves (wave = 16 rows), chunk range [lo,hi) of the
// tile's (tile+1) 64-wide s-chunks.  Writes unnormalized partial m/l/O(bf16).
// ---------------------------------------------------------------------------
__global__ __launch_bounds__(256)
void attn_mfma_kernel(const ushort* __restrict__ q, const ushort* __restrict__ k,
                      const ushort* __restrict__ vT,
                      float* __restrict__ partM, float* __restrict__ partL,
                      ushort* __restrict__ partO)
{
    __shared__ ushort qs[64 * 72];
    __shared__ ushort ks[64 * 72];
    __shared__ ushort vs[64 * 72];        // [d][s] (from vT)
    __shared__ ushort ps[4][16 * 72];     // wave-private P

    const int tid = threadIdx.x, w = tid >> 6, lane = tid & 63;
    const int m = lane & 15, quad = lane >> 4;
    const int pid = blockIdx.x;
    const int job = pid >> 2, split = pid & 3;
    const int b = job >> 6, tile = job & 63;
    const int i0 = tile * 64;
    const int nch = tile + 1;
    const int lo = (nch * split) >> 2, hi = (nch * (split + 1)) >> 2;

    // stage q tile
    const size_t qbase = ((size_t)b * TT + i0) * HH;
    #pragma unroll
    for (int it = 0; it < 2; ++it) {
        const int t2 = it * 256 + tid;
        const int r = t2 >> 3, seg = t2 & 7;
        *(uint4*)(qs + r * 72 + seg * 8) = *(const uint4*)(q + qbase + (size_t)r * HH + seg * 8);
    }
    __syncthreads();

    const short8 aq0 = *(const short8*)(qs + (w * 16 + m) * 72 + quad * 8);
    const short8 aq1 = *(const short8*)(qs + (w * 16 + m) * 72 + 32 + quad * 8);

    float mrow[4], lrow[4];
    floatx4 oacc[4];
    #pragma unroll
    for (int r = 0; r < 4; ++r) { mrow[r] = -1e30f; lrow[r] = 0.f; }
    #pragma unroll
    for (int nt = 0; nt < 4; ++nt) oacc[nt] = (floatx4){0.f, 0.f, 0.f, 0.f};

    const int iq0 = i0 + w * 16;
    for (int ch = lo; ch < hi; ++ch) {
        const int s0 = ch * 64;
        __syncthreads();
        const size_t kb = ((size_t)b * TT + s0) * HH;
        #pragma unroll
        for (int it = 0; it < 2; ++it) {
            const int t2 = it * 256 + tid;
            const int r = t2 >> 3, seg = t2 & 7;
            *(uint4*)(ks + r * 72 + seg * 8) = *(const uint4*)(k + kb + (size_t)r * HH + seg * 8);
            *(uint4*)(vs + r * 72 + seg * 8) = *(const uint4*)(vT + ((size_t)b * HH + r) * TT + s0 + seg * 8);
        }
        __syncthreads();

        // scores: 4 n-tiles x 2 k-steps
        floatx4 sc[4];
        #pragma unroll
        for (int nt = 0; nt < 4; ++nt) {
            const short8 b0 = *(const short8*)(ks + (nt * 16 + m) * 72 + quad * 8);
            const short8 b1 = *(const short8*)(ks + (nt * 16 + m) * 72 + 32 + quad * 8);
            floatx4 s_ = (floatx4){0.f, 0.f, 0.f, 0.f};
            s_ = __builtin_amdgcn_mfma_f32_16x16x32_bf16(aq0, b0, s_, 0, 0, 0);
            s_ = __builtin_amdgcn_mfma_f32_16x16x32_bf16(aq1, b1, s_, 0, 0, 0);
            sc[nt] = s_;
        }

        // online softmax (C-layout: col = nt*16+m, row = quad*4+r)
        #pragma unroll
        for (int r = 0; r < 4; ++r) {
            const int irow = iq0 + quad * 4 + r;
            float v0 = sc[0][r] * 0.125f, v1 = sc[1][r] * 0.125f;
            float v2 = sc[2][r] * 0.125f, v3 = sc[3][r] * 0.125f;
            if (s0      + m > irow) v0 = -1e30f;
            if (s0 + 16 + m > irow) v1 = -1e30f;
            if (s0 + 32 + m > irow) v2 = -1e30f;
            if (s0 + 48 + m > irow) v3 = -1e30f;
            float mx = fmaxf(fmaxf(v0, v1), fmaxf(v2, v3));
            mx = fmaxf(mx, __shfl_xor(mx, 1));
            mx = fmaxf(mx, __shfl_xor(mx, 2));
            mx = fmaxf(mx, __shfl_xor(mx, 4));
            mx = fmaxf(mx, __shfl_xor(mx, 8));
            const float mn = fmaxf(mrow[r], mx);
            const float alpha = __expf(mrow[r] - mn);
            mrow[r] = mn;
            v0 = __expf(v0 - mn); v1 = __expf(v1 - mn);
            v2 = __expf(v2 - mn); v3 = __expf(v3 - mn);
            float rs = v0 + v1 + v2 + v3;
            rs += __shfl_xor(rs, 1); rs += __shfl_xor(rs, 2);
            rs += __shfl_xor(rs, 4); rs += __shfl_xor(rs, 8);
            lrow[r] = lrow[r] * alpha + rs;
            oacc[0][r] *= alpha; oacc[1][r] *= alpha;
            oacc[2][r] *= alpha; oacc[3][r] *= alpha;
            ushort* pr = ps[w] + (quad * 4 + r) * 72;
            pr[m]      = f2bf(v0);
            pr[16 + m] = f2bf(v1);
            pr[32 + m] = f2bf(v2);
            pr[48 + m] = f2bf(v3);
        }

        // PV: A = P (LDS round-trip), B = vT rows
        #pragma unroll
        for (int ks_ = 0; ks_ < 2; ++ks_) {
            const short8 ap = *(const short8*)(ps[w] + m * 72 + ks_ * 32 + quad * 8);
            #pragma unroll
            for (int nt = 0; nt < 4; ++nt) {
                const short8 bv_ = *(const short8*)(vs + (nt * 16 + m) * 72 + ks_ * 32 + quad * 8);
                oacc[nt] = __builtin_amdgcn_mfma_f32_16x16x32_bf16(ap, bv_, oacc[nt], 0, 0, 0);
            }
        }
    }

    // epilogue: write partials (unnormalized)
    if (m == 0) {
        #pragma unroll
        for (int r = 0; r < 4; ++r) {
            const int row = w * 16 + quad * 4 + r;
            partM[(size_t)pid * 64 + row] = mrow[r];
            partL[(size_t)pid * 64 + row] = lrow[r];
        }
    }
    ushort* po = partO + ((size_t)pid * 64 + w * 16) * 64;
    #pragma unroll
    for (int r = 0; r < 4; ++r) {
        const int row = quad * 4 + r;
        #pragma unroll
        for (int nt = 0; nt < 4; ++nt)
            po[row * 64 + nt * 16 + m] = f2bf(oacc[nt][r]);
    }
}

// ---------------------------------------------------------------------------
// Kernel D: combine 4 split partials.  grid = 256 (job), 256 threads.
// thread: row = tid>>2, d-range = (tid&3)*16.
// ---------------------------------------------------------------------------
__global__ __launch_bounds__(256)
void attn_combine_kernel(const float* __restrict__ partM, const float* __restrict__ partL,
                         const ushort* __restrict__ partO, float* __restrict__ out)
{
    const int job = blockIdx.x;
    const int tid = threadIdx.x;
    const int row = tid >> 2, dq = tid & 3;

    float m[4], l[4];
    #pragma unroll
    for (int s = 0; s < 4; ++s) {
        m[s] = partM[(size_t)(job * 4 + s) * 64 + row];
        l[s] = partL[(size_t)(job * 4 + s) * 64 + row];
    }
    const float M = fmaxf(fmaxf(m[0], m[1]), fmaxf(m[2], m[3]));
    float sc[4], L = 0.f;
    #pragma unroll
    for (int s = 0; s < 4; ++s) { sc[s] = __expf(m[s] - M); L += l[s] * sc[s]; }
    const float inv = 1.f / L;

    float o[16];
    #pragma unroll
    for (int i = 0; i < 16; ++i) o[i] = 0.f;
    #pragma unroll
    for (int s = 0; s < 4; ++s) {
        const ushort* po = partO + (((size_t)(job * 4 + s) * 64 + row) * 64 + dq * 16);
        #pragma unroll
        for (int i2 = 0; i2 < 2; ++i2) {
            const ushort4 pa = *(const ushort4*)(po + i2 * 8);
            const ushort4 pb = *(const ushort4*)(po + i2 * 8 + 4);
            o[i2*8+0] = fmaf(bf2f(pa.x), sc[s], o[i2*8+0]);
            o[i2*8+1] = fmaf(bf2f(pa.y), sc[s], o[i2*8+1]);
            o[i2*8+2] = fmaf(bf2f(pa.z), sc[s], o[i2*8+2]);
            o[i2*8+3] = fmaf(bf2f(pa.w), sc[s], o[i2*8+3]);
            o[i2*8+4] = fmaf(bf2f(pb.x), sc[s], o[i2*8+4]);
            o[i2*8+5] = fmaf(bf2f(pb.y), sc[s], o[i2*8+5]);
            o[i2*8+6] = fmaf(bf2f(pb.z), sc[s], o[i2*8+6]);
            o[i2*8+7] = fmaf(bf2f(pb.w), sc[s], o[i2*8+7]);
        }
    }
    float4* dst = (float4*)(out + ((size_t)job * 64 + row) * 64 + dq * 16);
    #pragma unroll
    for (int i = 0; i < 4; ++i) {
        float4 v; v.x = o[i*4]*inv; v.y = o[i*4+1]*inv; v.z = o[i*4+2]*inv; v.w = o[i*4+3]*inv;
        dst[i] = v;
    }
}

extern "C" void kernel_launch(void* const* d_in, const int* in_sizes, int n_in,
                              void* d_out, int out_size, void* d_ws, size_t ws_size,
                              hipStream_t stream) {
    (void)in_sizes; (void)n_in; (void)out_size; (void)ws_size;
    const float* x  = (const float*)d_in[0];
    // d_in[1] = causal mask, structural -> unused
    const float* Wq = (const float*)d_in[2];
    const float* bq = (const float*)d_in[3];
    const float* Wk = (const float*)d_in[4];
    const float* bk = (const float*)d_in[5];
    const float* Wv = (const float*)d_in[6];
    const float* bv = (const float*)d_in[7];
    float* out = (float*)d_out;

    char* ws = (char*)d_ws;
    ushort* wT    = (ushort*)ws;                          // 384 KB
    ushort* qb    = (ushort*)(ws + 393216);               // 2 MB
    ushort* kb    = qb + (size_t)BB * TT * HH;            // 2 MB
    ushort* vTb   = kb + (size_t)BB * TT * HH;            // 2 MB
    float*  partM = (float*) (ws + 6684672);              // 256 KB
    float*  partL = (float*) (ws + 6946816);              // 256 KB
    ushort* partO = (ushort*)(ws + 7208960);              // 8.4 MB  (total ~15.6 MB)

    wtrans_kernel   <<<192, 256, 0, stream>>>(Wq, Wk, Wv, wT);
    qkv_mfma_kernel <<<(BB * TT) / 32, 512, 0, stream>>>(x, wT, bq, bk, bv, qb, kb, vTb);
    attn_mfma_kernel<<<BB * 64 * 4, 256, 0, stream>>>(qb, kb, vTb, partM, partL, partO);
    attn_combine_kernel<<<BB * 64, 256, 0, stream>>>(partM, partL, partO, out);
}